// Round 5
// baseline (379.548 us; speedup 1.0000x reference)
//
#include <hip/hip_runtime.h>
#include <math.h>
#include <type_traits>

#define NCH 48            // N*C = 16*3
#define WIN 11
#define HALO 10
#define BW 64             // output tile width
#define BH 32             // output tile height
#define IW 74             // BW + HALO
#define IH 42             // BH + HALO

struct GaussW { float g[WIN]; };

// ---- bf16 <-> f32 bit helpers (RNE pack) ----
__device__ __forceinline__ float bf2f(unsigned u16)      // u16 in low 16 bits
{
    return __uint_as_float(u16 << 16);
}
__device__ __forceinline__ unsigned f2bf(float f)        // returns low-16 bf16
{
    unsigned u = __float_as_uint(f);
    u += 0x7FFFu + ((u >> 16) & 1u);                     // round-to-nearest-even
    return u >> 16;
}

// element load/store wrappers
__device__ __forceinline__ float eload(const unsigned short* p) { return bf2f(*p); }
__device__ __forceinline__ float eload(const float* p)          { return *p; }
__device__ __forceinline__ void  estore(unsigned short* p, float v) { *p = (unsigned short)f2bf(v); }
__device__ __forceinline__ void  estore(float* p, float v)          { *p = v; }

// vertical blur of NOUT consecutive output rows at column c
template<int NOUT, typename ET, int LS>
__device__ __forceinline__ void vblur_col(const ET (*sX)[LS], const ET (*sY)[LS],
                                          ET (*vb)[BH][LS],
                                          int r0, int c, const GaussW& gw)
{
    float a0[NOUT], a1[NOUT], a2[NOUT], a3[NOUT], a4[NOUT];
#pragma unroll
    for (int j = 0; j < NOUT; ++j) { a0[j] = a1[j] = a2[j] = a3[j] = a4[j] = 0.f; }
#pragma unroll
    for (int i = 0; i < NOUT + 10; ++i) {
        float xv = eload(&sX[r0 + i][c]);
        float yv = eload(&sY[r0 + i][c]);
        float xx = xv * xv, yy = yv * yv, xy = xv * yv;
#pragma unroll
        for (int j = 0; j < NOUT; ++j) {
            int k = i - j;
            if (k >= 0 && k < WIN) {
                float gv = gw.g[k];
                a0[j] += gv * xv;
                a1[j] += gv * yv;
                a2[j] += gv * xx;
                a3[j] += gv * yy;
                a4[j] += gv * xy;
            }
        }
    }
#pragma unroll
    for (int j = 0; j < NOUT; ++j) {
        estore(&vb[0][r0 + j][c], a0[j]);
        estore(&vb[1][r0 + j][c], a1[j]);
        estore(&vb[2][r0 + j][c], a2[j]);
        estore(&vb[3][r0 + j][c], a3[j]);
        estore(&vb[4][r0 + j][c], a4[j]);
    }
}

// ---------------------------------------------------------------------------
// Fused per-level kernel: one block = one 64x32 output tile of one (n,c).
// LP=true : bf16 LDS (39 KB) -> 4 blocks/CU. Used for levels 0-1 where the
//           sigma cancellation (sxx - mu^2) has a large denominator, so the
//           bf16 Jensen ratio bias is <1e-4 relative. (Level>=2 it is NOT.)
// LP=false: fp32 LDS (74 KB) -> 2 blocks/CU. Levels 2-4 (tiny grids).
// ---------------------------------------------------------------------------
template<bool LP>
__global__ __launch_bounds__(512, LP ? 8 : 4)
void ssim_level_kernel(const float* __restrict__ X, const float* __restrict__ Y,
                       int H, int W, int outH, int outW,
                       float* __restrict__ accS2, float* __restrict__ accD,
                       float* __restrict__ poolX, float* __restrict__ poolY,
                       GaussW gw)
{
    using ET = std::conditional_t<LP, unsigned short, float>;
    constexpr int LS = LP ? 80 : 76;     // row stride: 160 B / 304 B (mult 16)

    const int nc  = blockIdx.z;
    const int oy0 = blockIdx.y * BH;
    const int ox0 = blockIdx.x * BW;
    const int tid = threadIdx.x;

    const float* __restrict__ Xp = X + (size_t)nc * H * W;
    const float* __restrict__ Yp = Y + (size_t)nc * H * W;

    __shared__ __align__(16) ET sX[IH][LS];
    __shared__ __align__(16) ET sY[IH][LS];
    __shared__ __align__(16) ET vb[5][BH][LS];   // mu1,mu2,xx,yy,xy (V-blurred)
    __shared__ float wpart[2][8];

    // ---- stage input tile; OOB -> 0 ----
    for (int l = tid; l < IH * 37; l += 512) {   // 42 rows x 37 pairs (74 cols)
        int r  = l / 37, cp = l - r * 37;
        int gy = oy0 + r, gx = ox0 + 2 * cp;
        float2 xv = make_float2(0.f, 0.f), yv = xv;
        if (gy < H && gx < W) {                  // W even, gx even -> gx+1 < W
            size_t idx = (size_t)gy * W + gx;
            xv = *(const float2*)(Xp + idx);
            yv = *(const float2*)(Yp + idx);
        }
        if constexpr (LP) {
            ((unsigned*)sX[r])[cp] = f2bf(xv.x) | (f2bf(xv.y) << 16);
            ((unsigned*)sY[r])[cp] = f2bf(yv.x) | (f2bf(yv.y) << 16);
        } else {
            sX[r][2 * cp]     = xv.x;
            sX[r][2 * cp + 1] = xv.y;
            sY[r][2 * cp]     = yv.x;
            sY[r][2 * cp + 1] = yv.y;
        }
    }
    __syncthreads();

    // ---- fused 2x2 avg-pool of raw 64x32 quadrant -> 32x16 pooled tile ----
    if (poolX) {
        int py = tid >> 5, px = tid & 31;        // 16 rows x 32 cols
        int pH = H >> 1, pW = W >> 1;
        int ppy = (oy0 >> 1) + py, ppx = (ox0 >> 1) + px;
        if (ppy < pH && ppx < pW) {
            float vx, vy;
            if constexpr (LP) {
                unsigned x0 = ((unsigned*)sX[2 * py])[px];
                unsigned x1 = ((unsigned*)sX[2 * py + 1])[px];
                unsigned y0 = ((unsigned*)sY[2 * py])[px];
                unsigned y1 = ((unsigned*)sY[2 * py + 1])[px];
                vx = 0.25f * (bf2f(x0 & 0xffffu) + bf2f(x0 >> 16) +
                              bf2f(x1 & 0xffffu) + bf2f(x1 >> 16));
                vy = 0.25f * (bf2f(y0 & 0xffffu) + bf2f(y0 >> 16) +
                              bf2f(y1 & 0xffffu) + bf2f(y1 >> 16));
            } else {
                vx = 0.25f * (sX[2 * py][2 * px]     + sX[2 * py][2 * px + 1] +
                              sX[2 * py + 1][2 * px] + sX[2 * py + 1][2 * px + 1]);
                vy = 0.25f * (sY[2 * py][2 * px]     + sY[2 * py][2 * px + 1] +
                              sY[2 * py + 1][2 * px] + sY[2 * py + 1][2 * px + 1]);
            }
            size_t o = ((size_t)nc * pH + ppy) * pW + ppx;
            poolX[o] = vx;
            poolY[o] = vy;
        }
    }

    // ---- vertical blur: 74 cols x (5 full 6-row groups + one 2-row tail) ----
    if (tid < IW * 6) {
        int rg = tid / IW, c = tid - rg * IW;
        if (rg < 5) vblur_col<6, ET, LS>(sX, sY, vb, rg * 6, c, gw);
        else        vblur_col<2, ET, LS>(sX, sY, vb, 30, c, gw);
    }
    __syncthreads();

    // ---- horizontal blur + SSIM; 4 outputs/thread ----
    const float C1 = 1e-4f, C2 = 9e-4f;
    float locS2 = 0.f, locD = 0.f;
    {
        const int r  = tid >> 4;                 // 0..31
        const int cb = (tid & 15) * 4;           // 0..60
        float st[5][4];
#pragma unroll
        for (int s = 0; s < 5; ++s) {
            float w[16];
            if constexpr (LP) {
                const uint2* p = (const uint2*)(&vb[s][r][cb]);  // 8B aligned
                uint2 q0 = p[0], q1 = p[1], q2 = p[2], q3 = p[3];
                unsigned wd[7] = {q0.x, q0.y, q1.x, q1.y, q2.x, q2.y, q3.x};
#pragma unroll
                for (int i = 0; i < 7; ++i) {
                    w[2 * i]     = bf2f(wd[i] & 0xffffu);
                    w[2 * i + 1] = bf2f(wd[i] >> 16);
                }
            } else {
                const float4* p = (const float4*)(&vb[s][r][cb]); // 16B aligned
                float4 q0 = p[0], q1 = p[1], q2 = p[2], q3 = p[3];
                float tmp[16] = {q0.x, q0.y, q0.z, q0.w, q1.x, q1.y, q1.z, q1.w,
                                 q2.x, q2.y, q2.z, q2.w, q3.x, q3.y, q3.z, q3.w};
#pragma unroll
                for (int i = 0; i < 16; ++i) w[i] = tmp[i];
            }
#pragma unroll
            for (int j = 0; j < 4; ++j) {
                float acc = 0.f;
#pragma unroll
                for (int k = 0; k < WIN; ++k) acc += gw.g[k] * w[j + k];
                st[s][j] = acc;
            }
        }
        const int oy = oy0 + r;
#pragma unroll
        for (int j = 0; j < 4; ++j) {
            int ox = ox0 + cb + j;
            if (oy < outH && ox < outW) {
                float mu1 = st[0][j], mu2 = st[1][j];
                float mu1sq = mu1 * mu1, mu2sq = mu2 * mu2, mu12 = mu1 * mu2;
                float s1  = st[2][j] - mu1sq;
                float s2v = st[3][j] - mu2sq;
                float s12 = st[4][j] - mu12;
                float S1 = (2.f * mu12 + C1) * __builtin_amdgcn_rcpf(mu1sq + mu2sq + C1);
                float S2 = (2.f * s12 + C2) * __builtin_amdgcn_rcpf(s1 + s2v + C2);
                float S  = S1 + S2;
                if (S > 2.f) S = 2.f;
                locS2 += S2;
                locD  += __builtin_amdgcn_sqrtf(2.f - S);
            }
        }
    }

    // ---- block reduction: wave shuffle, then 8 wave partials ----
#pragma unroll
    for (int off = 32; off > 0; off >>= 1) {
        locS2 += __shfl_down(locS2, off);
        locD  += __shfl_down(locD,  off);
    }
    if ((tid & 63) == 0) {
        wpart[0][tid >> 6] = locS2;
        wpart[1][tid >> 6] = locD;
    }
    __syncthreads();
    if (tid == 0) {
        float s = 0.f, d = 0.f;
#pragma unroll
        for (int i = 0; i < 8; ++i) { s += wpart[0][i]; d += wpart[1][i]; }
        atomicAdd(&accS2[nc], s);
        atomicAdd(&accD[nc],  d);
    }
}

// ---------------------------------------------------------------------------
__global__ void zero_acc_kernel(float* acc, int n)
{
    int i = blockIdx.x * blockDim.x + threadIdx.x;
    if (i < n) acc[i] = 0.f;
}

// finalize: per-(n,c) weighted product over levels, mean -> scalar
// acc layout per level: [lvl*96 + 0..47] = sum S2, [lvl*96 + 48..95] = sum D
__global__ void finalize_kernel(const float* __restrict__ acc, float* __restrict__ out)
{
    int t = threadIdx.x;
    float v = 0.f;
    if (t < NCH) {
        const float w[5]   = {0.0448f, 0.2856f, 0.3001f, 0.2363f, 0.1333f};
        const float cnt[5] = {502.f * 502.f, 246.f * 246.f, 118.f * 118.f,
                              54.f * 54.f, 22.f * 22.f};
        float val = 1.f;
#pragma unroll
        for (int l = 0; l < 4; ++l) {
            float cs = fmaxf(acc[l * 96 + t] / cnt[l], 0.f);
            val *= powf(cs, w[l]);
        }
        float d = fmaxf(acc[4 * 96 + 48 + t] / cnt[4], 0.f);
        val *= powf(d, w[4]);
        v = val;
    }
#pragma unroll
    for (int off = 32; off > 0; off >>= 1) v += __shfl_down(v, off);
    if (t == 0) out[0] = v / (float)NCH;
}

// ---------------------------------------------------------------------------
static GaussW make_gauss()
{
    GaussW gw;
    double v[WIN], s = 0.0;
    for (int i = 0; i < WIN; ++i) {
        double c = (double)i - (WIN / 2);
        v[i] = exp(-c * c / (2.0 * 1.5 * 1.5));
        s += v[i];
    }
    for (int i = 0; i < WIN; ++i) gw.g[i] = (float)(v[i] / s);
    return gw;
}

extern "C" void kernel_launch(void* const* d_in, const int* in_sizes, int n_in,
                              void* d_out, int out_size, void* d_ws, size_t ws_size,
                              hipStream_t stream)
{
    const float* X0 = (const float*)d_in[0];
    const float* Y0 = (const float*)d_in[1];
    float* out = (float*)d_out;
    char*  ws  = (char*)d_ws;

    float* acc = (float*)ws;                 // 5 levels x 96 floats
    const int accN = 5 * 96;
    zero_acc_kernel<<<(accN + 255) / 256, 256, 0, stream>>>(acc, accN);

    float* pyr = (float*)(ws + 4096);
    GaussW gw = make_gauss();

    const float* curX = X0;
    const float* curY = Y0;
    float* nextbuf = pyr;
    int H = 512;

    for (int lvl = 0; lvl < 5; ++lvl) {
        int outH = H - HALO;
        int gx = H / BW; if (gx == 0) gx = 1;
        int gy = H / BH;
        dim3 grid(gx, gy, NCH);

        float* nX = nullptr;
        float* nY = nullptr;
        if (lvl < 4) {
            int oh = H / 2;
            size_t elems = (size_t)NCH * oh * oh;
            nX = nextbuf;
            nY = nX + elems;
            nextbuf = nY + elems;
        }

        if (lvl < 2) {
            ssim_level_kernel<true><<<grid, 512, 0, stream>>>(
                curX, curY, H, H, outH, outH,
                acc + lvl * 96, acc + lvl * 96 + 48, nX, nY, gw);
        } else {
            ssim_level_kernel<false><<<grid, 512, 0, stream>>>(
                curX, curY, H, H, outH, outH,
                acc + lvl * 96, acc + lvl * 96 + 48, nX, nY, gw);
        }

        if (lvl < 4) {
            curX = nX;
            curY = nY;
            H >>= 1;
        }
    }

    finalize_kernel<<<1, 64, 0, stream>>>(acc, out);
}

// Round 6
// 257.756 us; speedup vs baseline: 1.4725x; 1.4725x over previous
//
#include <hip/hip_runtime.h>
#include <math.h>
#include <type_traits>

#define NCH 48            // N*C = 16*3
#define WIN 11
#define HALO 10
#define BW 64             // output tile width
#define BH 32             // output tile height
#define IW 74             // BW + HALO
#define IH 42             // BH + HALO

struct GaussW { float g[WIN]; };

// ---- bf16 <-> f32 bit helpers (RNE pack) ----
__device__ __forceinline__ float bf2f(unsigned u16)      // u16 in low 16 bits
{
    return __uint_as_float(u16 << 16);
}
__device__ __forceinline__ unsigned f2bf(float f)        // returns low-16 bf16
{
    unsigned u = __float_as_uint(f);
    u += 0x7FFFu + ((u >> 16) & 1u);                     // round-to-nearest-even
    return u >> 16;
}

// element load/store wrappers
__device__ __forceinline__ float eload(const unsigned short* p) { return bf2f(*p); }
__device__ __forceinline__ float eload(const float* p)          { return *p; }
__device__ __forceinline__ void  estore(unsigned short* p, float v) { *p = (unsigned short)f2bf(v); }
__device__ __forceinline__ void  estore(float* p, float v)          { *p = v; }

// vertical blur of NOUT consecutive output rows at column c
template<int NOUT, typename ET, int LS>
__device__ __forceinline__ void vblur_col(const ET (*sX)[LS], const ET (*sY)[LS],
                                          ET (*vb)[BH][LS],
                                          int r0, int c, const GaussW& gw)
{
    float a0[NOUT], a1[NOUT], a2[NOUT], a3[NOUT], a4[NOUT];
#pragma unroll
    for (int j = 0; j < NOUT; ++j) { a0[j] = a1[j] = a2[j] = a3[j] = a4[j] = 0.f; }
#pragma unroll
    for (int i = 0; i < NOUT + 10; ++i) {
        float xv = eload(&sX[r0 + i][c]);
        float yv = eload(&sY[r0 + i][c]);
        float xx = xv * xv, yy = yv * yv, xy = xv * yv;
#pragma unroll
        for (int j = 0; j < NOUT; ++j) {
            int k = i - j;
            if (k >= 0 && k < WIN) {
                float gv = gw.g[k];
                a0[j] += gv * xv;
                a1[j] += gv * yv;
                a2[j] += gv * xx;
                a3[j] += gv * yy;
                a4[j] += gv * xy;
            }
        }
    }
#pragma unroll
    for (int j = 0; j < NOUT; ++j) {
        estore(&vb[0][r0 + j][c], a0[j]);
        estore(&vb[1][r0 + j][c], a1[j]);
        estore(&vb[2][r0 + j][c], a2[j]);
        estore(&vb[3][r0 + j][c], a3[j]);
        estore(&vb[4][r0 + j][c], a4[j]);
    }
}

// ---------------------------------------------------------------------------
// Fused per-level kernel: one block = one 64x32 output tile of one (n,c).
// LP=true : bf16 LDS (39 KB). __launch_bounds__(512,6): VGPR cap 85 -- NO
//           spills (R5 lesson: (512,8) forced 32 VGPR -> 350MB scratch
//           traffic, 1.7x regression). 3 blocks/CU, 24 waves.
// LP=false: fp32 LDS (74 KB) -> 2 blocks/CU. Levels 2-4 (tiny grids, and
//           bf16's sigma-cancellation bias is too large at those levels).
// ---------------------------------------------------------------------------
template<bool LP>
__global__ __launch_bounds__(512, LP ? 6 : 4)
void ssim_level_kernel(const float* __restrict__ X, const float* __restrict__ Y,
                       int H, int W, int outH, int outW,
                       float* __restrict__ accS2, float* __restrict__ accD,
                       float* __restrict__ poolX, float* __restrict__ poolY,
                       GaussW gw)
{
    using ET = std::conditional_t<LP, unsigned short, float>;
    constexpr int LS = LP ? 80 : 76;     // row stride: 160 B / 304 B (mult 16)

    const int nc  = blockIdx.z;
    const int oy0 = blockIdx.y * BH;
    const int ox0 = blockIdx.x * BW;
    const int tid = threadIdx.x;

    const float* __restrict__ Xp = X + (size_t)nc * H * W;
    const float* __restrict__ Yp = Y + (size_t)nc * H * W;

    __shared__ __align__(16) ET sX[IH][LS];
    __shared__ __align__(16) ET sY[IH][LS];
    __shared__ __align__(16) ET vb[5][BH][LS];   // mu1,mu2,xx,yy,xy (V-blurred)
    __shared__ float wpart[2][8];

    // ---- stage input tile; OOB -> 0 ----
    for (int l = tid; l < IH * 37; l += 512) {   // 42 rows x 37 pairs (74 cols)
        int r  = l / 37, cp = l - r * 37;
        int gy = oy0 + r, gx = ox0 + 2 * cp;
        float2 xv = make_float2(0.f, 0.f), yv = xv;
        if (gy < H && gx < W) {                  // W even, gx even -> gx+1 < W
            size_t idx = (size_t)gy * W + gx;
            xv = *(const float2*)(Xp + idx);
            yv = *(const float2*)(Yp + idx);
        }
        if constexpr (LP) {
            ((unsigned*)sX[r])[cp] = f2bf(xv.x) | (f2bf(xv.y) << 16);
            ((unsigned*)sY[r])[cp] = f2bf(yv.x) | (f2bf(yv.y) << 16);
        } else {
            sX[r][2 * cp]     = xv.x;
            sX[r][2 * cp + 1] = xv.y;
            sY[r][2 * cp]     = yv.x;
            sY[r][2 * cp + 1] = yv.y;
        }
    }
    __syncthreads();

    // ---- fused 2x2 avg-pool of raw 64x32 quadrant -> 32x16 pooled tile ----
    if (poolX) {
        int py = tid >> 5, px = tid & 31;        // 16 rows x 32 cols
        int pH = H >> 1, pW = W >> 1;
        int ppy = (oy0 >> 1) + py, ppx = (ox0 >> 1) + px;
        if (ppy < pH && ppx < pW) {
            float vx, vy;
            if constexpr (LP) {
                unsigned x0 = ((unsigned*)sX[2 * py])[px];
                unsigned x1 = ((unsigned*)sX[2 * py + 1])[px];
                unsigned y0 = ((unsigned*)sY[2 * py])[px];
                unsigned y1 = ((unsigned*)sY[2 * py + 1])[px];
                vx = 0.25f * (bf2f(x0 & 0xffffu) + bf2f(x0 >> 16) +
                              bf2f(x1 & 0xffffu) + bf2f(x1 >> 16));
                vy = 0.25f * (bf2f(y0 & 0xffffu) + bf2f(y0 >> 16) +
                              bf2f(y1 & 0xffffu) + bf2f(y1 >> 16));
            } else {
                vx = 0.25f * (sX[2 * py][2 * px]     + sX[2 * py][2 * px + 1] +
                              sX[2 * py + 1][2 * px] + sX[2 * py + 1][2 * px + 1]);
                vy = 0.25f * (sY[2 * py][2 * px]     + sY[2 * py][2 * px + 1] +
                              sY[2 * py + 1][2 * px] + sY[2 * py + 1][2 * px + 1]);
            }
            size_t o = ((size_t)nc * pH + ppy) * pW + ppx;
            poolX[o] = vx;
            poolY[o] = vy;
        }
    }

    // ---- vertical blur: 74 cols x (5 full 6-row groups + one 2-row tail) ----
    if (tid < IW * 6) {
        int rg = tid / IW, c = tid - rg * IW;
        if (rg < 5) vblur_col<6, ET, LS>(sX, sY, vb, rg * 6, c, gw);
        else        vblur_col<2, ET, LS>(sX, sY, vb, 30, c, gw);
    }
    __syncthreads();

    // ---- horizontal blur + SSIM; 4 outputs/thread ----
    const float C1 = 1e-4f, C2 = 9e-4f;
    float locS2 = 0.f, locD = 0.f;
    {
        const int r  = tid >> 4;                 // 0..31
        const int cb = (tid & 15) * 4;           // 0..60
        float st[5][4];
#pragma unroll
        for (int s = 0; s < 5; ++s) {
            float w[16];
            if constexpr (LP) {
                const uint2* p = (const uint2*)(&vb[s][r][cb]);  // 8B aligned
                uint2 q0 = p[0], q1 = p[1], q2 = p[2], q3 = p[3];
                unsigned wd[7] = {q0.x, q0.y, q1.x, q1.y, q2.x, q2.y, q3.x};
#pragma unroll
                for (int i = 0; i < 7; ++i) {
                    w[2 * i]     = bf2f(wd[i] & 0xffffu);
                    w[2 * i + 1] = bf2f(wd[i] >> 16);
                }
            } else {
                const float4* p = (const float4*)(&vb[s][r][cb]); // 16B aligned
                float4 q0 = p[0], q1 = p[1], q2 = p[2], q3 = p[3];
                float tmp[16] = {q0.x, q0.y, q0.z, q0.w, q1.x, q1.y, q1.z, q1.w,
                                 q2.x, q2.y, q2.z, q2.w, q3.x, q3.y, q3.z, q3.w};
#pragma unroll
                for (int i = 0; i < 16; ++i) w[i] = tmp[i];
            }
#pragma unroll
            for (int j = 0; j < 4; ++j) {
                float acc = 0.f;
#pragma unroll
                for (int k = 0; k < WIN; ++k) acc += gw.g[k] * w[j + k];
                st[s][j] = acc;
            }
        }
        const int oy = oy0 + r;
#pragma unroll
        for (int j = 0; j < 4; ++j) {
            int ox = ox0 + cb + j;
            if (oy < outH && ox < outW) {
                float mu1 = st[0][j], mu2 = st[1][j];
                float mu1sq = mu1 * mu1, mu2sq = mu2 * mu2, mu12 = mu1 * mu2;
                float s1  = st[2][j] - mu1sq;
                float s2v = st[3][j] - mu2sq;
                float s12 = st[4][j] - mu12;
                float S1 = (2.f * mu12 + C1) * __builtin_amdgcn_rcpf(mu1sq + mu2sq + C1);
                float S2 = (2.f * s12 + C2) * __builtin_amdgcn_rcpf(s1 + s2v + C2);
                float S  = S1 + S2;
                if (S > 2.f) S = 2.f;
                locS2 += S2;
                locD  += __builtin_amdgcn_sqrtf(2.f - S);
            }
        }
    }

    // ---- block reduction: wave shuffle, then 8 wave partials ----
#pragma unroll
    for (int off = 32; off > 0; off >>= 1) {
        locS2 += __shfl_down(locS2, off);
        locD  += __shfl_down(locD,  off);
    }
    if ((tid & 63) == 0) {
        wpart[0][tid >> 6] = locS2;
        wpart[1][tid >> 6] = locD;
    }
    __syncthreads();
    if (tid == 0) {
        float s = 0.f, d = 0.f;
#pragma unroll
        for (int i = 0; i < 8; ++i) { s += wpart[0][i]; d += wpart[1][i]; }
        atomicAdd(&accS2[nc], s);
        atomicAdd(&accD[nc],  d);
    }
}

// ---------------------------------------------------------------------------
__global__ void zero_acc_kernel(float* acc, int n)
{
    int i = blockIdx.x * blockDim.x + threadIdx.x;
    if (i < n) acc[i] = 0.f;
}

// finalize: per-(n,c) weighted product over levels, mean -> scalar
// acc layout per level: [lvl*96 + 0..47] = sum S2, [lvl*96 + 48..95] = sum D
__global__ void finalize_kernel(const float* __restrict__ acc, float* __restrict__ out)
{
    int t = threadIdx.x;
    float v = 0.f;
    if (t < NCH) {
        const float w[5]   = {0.0448f, 0.2856f, 0.3001f, 0.2363f, 0.1333f};
        const float cnt[5] = {502.f * 502.f, 246.f * 246.f, 118.f * 118.f,
                              54.f * 54.f, 22.f * 22.f};
        float val = 1.f;
#pragma unroll
        for (int l = 0; l < 4; ++l) {
            float cs = fmaxf(acc[l * 96 + t] / cnt[l], 0.f);
            val *= powf(cs, w[l]);
        }
        float d = fmaxf(acc[4 * 96 + 48 + t] / cnt[4], 0.f);
        val *= powf(d, w[4]);
        v = val;
    }
#pragma unroll
    for (int off = 32; off > 0; off >>= 1) v += __shfl_down(v, off);
    if (t == 0) out[0] = v / (float)NCH;
}

// ---------------------------------------------------------------------------
static GaussW make_gauss()
{
    GaussW gw;
    double v[WIN], s = 0.0;
    for (int i = 0; i < WIN; ++i) {
        double c = (double)i - (WIN / 2);
        v[i] = exp(-c * c / (2.0 * 1.5 * 1.5));
        s += v[i];
    }
    for (int i = 0; i < WIN; ++i) gw.g[i] = (float)(v[i] / s);
    return gw;
}

extern "C" void kernel_launch(void* const* d_in, const int* in_sizes, int n_in,
                              void* d_out, int out_size, void* d_ws, size_t ws_size,
                              hipStream_t stream)
{
    const float* X0 = (const float*)d_in[0];
    const float* Y0 = (const float*)d_in[1];
    float* out = (float*)d_out;
    char*  ws  = (char*)d_ws;

    float* acc = (float*)ws;                 // 5 levels x 96 floats
    const int accN = 5 * 96;
    zero_acc_kernel<<<(accN + 255) / 256, 256, 0, stream>>>(acc, accN);

    float* pyr = (float*)(ws + 4096);
    GaussW gw = make_gauss();

    const float* curX = X0;
    const float* curY = Y0;
    float* nextbuf = pyr;
    int H = 512;

    for (int lvl = 0; lvl < 5; ++lvl) {
        int outH = H - HALO;
        int gx = H / BW; if (gx == 0) gx = 1;
        int gy = H / BH;
        dim3 grid(gx, gy, NCH);

        float* nX = nullptr;
        float* nY = nullptr;
        if (lvl < 4) {
            int oh = H / 2;
            size_t elems = (size_t)NCH * oh * oh;
            nX = nextbuf;
            nY = nX + elems;
            nextbuf = nY + elems;
        }

        if (lvl < 2) {
            ssim_level_kernel<true><<<grid, 512, 0, stream>>>(
                curX, curY, H, H, outH, outH,
                acc + lvl * 96, acc + lvl * 96 + 48, nX, nY, gw);
        } else {
            ssim_level_kernel<false><<<grid, 512, 0, stream>>>(
                curX, curY, H, H, outH, outH,
                acc + lvl * 96, acc + lvl * 96 + 48, nX, nY, gw);
        }

        if (lvl < 4) {
            curX = nX;
            curY = nY;
            H >>= 1;
        }
    }

    finalize_kernel<<<1, 64, 0, stream>>>(acc, out);
}